// Round 5
// baseline (102.518 us; speedup 1.0000x reference)
//
#include <hip/hip_runtime.h>

// YOLOv1 head post-process. One block (1024 thr = 16 waves) per batch image.
// R5 synthesis of measured lessons:
//   R1->R2: serial shuffle-argmax NMS was ~60us — rank-count + scan wins.
//   R2->R3: writer store pattern is NOT the bottleneck (0 delta).
//   R4: per-class rank-space IoU rebuild cost more VALU than shfl-scan saved;
//       16B-stride rankbox LDS reads doubled bank conflicts (298K->700K).
// Design: class-independent IoU adjacency built ONCE (only for union-candidate
// boxes), stored as split u64 arrays (8B stride = conflict-free); per-class
// rank-count stable sort + register shfl greedy scan (dep chain ~5 ops/iter);
// 16 waves -> max 2 serial classes per wave; 1-iteration loader/writer.
// Equivalence notes:
//  * score < SCORE_T boxes only suppress even-lower-sorted boxes (all zeroed
//    by the final score filter) -> NMS over score>=SCORE_T candidates exact.
//  * candidate => conf*maxprob >= SCORE_T in float (prob_c <= 1/sum = maxprob
//    and x->rnd(x*conf), x->rnd(x/sum) are monotone) -> union skip is exact.
//  * rank tie-break = box index ascending = jnp stable argsort(-scores).
//  * K>64 per class (prob ~0) falls back to ballot-greedy (exact, slow).

namespace {
constexpr int kS    = 7;
constexpr int kC    = 20;
constexpr int kFeat = 30;             // C + 5*BBOX
constexpr int kN    = 98;             // S*S*2 boxes
constexpr int kRows = kN * kC;        // 1960
constexpr int kOutF = kRows * 6;      // 11760 floats per batch
constexpr int kT    = 1024;           // threads per block (16 waves)
constexpr float kIouT   = 0.5f;
constexpr float kScoreT = 0.05f;
}

__device__ __forceinline__ float iou_f(float ax1, float ay1, float ax2, float ay2,
                                       float bx1, float by1, float bx2, float by2) {
#pragma clang fp contract(off)
    float aa = fmaxf(ax2 - ax1, 0.f) * fmaxf(ay2 - ay1, 0.f);
    float ab = fmaxf(bx2 - bx1, 0.f) * fmaxf(by2 - by1, 0.f);
    float ix1 = fmaxf(ax1, bx1);
    float iy1 = fmaxf(ay1, by1);
    float ix2 = fminf(ax2, bx2);
    float iy2 = fminf(ay2, by2);
    float inter = fmaxf(ix2 - ix1, 0.f) * fmaxf(iy2 - iy1, 0.f);
    float uni = aa + ab - inter;
    return inter / fmaxf(uni, 1e-9f);
}

__device__ __forceinline__ unsigned long long shfl64(unsigned long long v, int src) {
    unsigned lo = (unsigned)__shfl((int)(unsigned)(v & 0xffffffffull), src);
    unsigned hi = (unsigned)__shfl((int)(unsigned)(v >> 32), src);
    return ((unsigned long long)hi << 32) | lo;
}

__global__ __launch_bounds__(kT, 8) void yolo_head_kernel(const float* __restrict__ x,
                                                          float* __restrict__ out) {
    __shared__ float xs[kS * kS * kFeat];                   // 1470 input floats
    __shared__ float scT[kC * kN];                          // scores [c][n]
    __shared__ float maxp[kS * kS];                         // 1/sum = max prob
    __shared__ __align__(16) float bxs[kN * 4];             // boxes [n][4]
    __shared__ unsigned long long adjLo[kN];                // row bits 0..63
    __shared__ unsigned long long adjHi[kN];                // row bits 64..97
    __shared__ float cscore[16][kN];                        // per-wave cand scores
    __shared__ unsigned short cidx[16][kN];                 // per-wave cand box idx
    __shared__ unsigned short rnk[16][64];                  // per-wave cand -> rank
    __shared__ unsigned short rid[16][64];                  // per-wave rank -> box
    __shared__ unsigned km[kC][4];                          // keep bitmask per class

    const int b   = blockIdx.x;
    const int tid = threadIdx.x;
    const float* xb = x + (size_t)b * (kS * kS * kFeat);

    // ---- load: 1470 floats = 735 float2, one iteration ----
    if (tid < (kS * kS * kFeat) / 2) {
        reinterpret_cast<float2*>(xs)[tid] =
            reinterpret_cast<const float2*>(xb)[tid];
    }
    __syncthreads();

    // ---- softmax (wave 0) and box decode (waves 1-2) in parallel ----
    if (tid < kS * kS) {
#pragma clang fp contract(off)
        const int cell = tid;
        const float* p = &xs[cell * kFeat];
        float mx = p[0];
        for (int c = 1; c < kC; ++c) mx = fmaxf(mx, p[c]);
        float e[kC];
        float sum = 0.f;
        for (int c = 0; c < kC; ++c) { e[c] = expf(p[c] - mx); sum += e[c]; }
        float conf0 = p[28], conf1 = p[29];
        for (int c = 0; c < kC; ++c) {
            float pr = e[c] / sum;
            scT[c * kN + 2 * cell]     = pr * conf0;
            scT[c * kN + 2 * cell + 1] = pr * conf1;
        }
        maxp[cell] = 1.0f / sum;    // exp(0)=1 is the max of e[] exactly
    } else if (tid >= 64 && tid < 64 + kN) {
#pragma clang fp contract(off)
        const int n = tid - 64;
        const int cell = n >> 1, k = n & 1;
        const int gi = cell / kS, gj = cell % kS;   // gy=gi, gx=gj
        const float* p = &xs[cell * kFeat + kC + 4 * k];
        float cx = (p[0] + (float)gj) / 7.0f;
        float cy = (p[1] + (float)gi) / 7.0f;
        float w = p[2], h = p[3];
        float4 bb;
        bb.x = fminf(fmaxf(cx - w * 0.5f, 0.f), 1.f) * 448.f;
        bb.y = fminf(fmaxf(cy - h * 0.5f, 0.f), 1.f) * 448.f;
        bb.z = fminf(fmaxf(cx + w * 0.5f, 0.f), 1.f) * 448.f;
        bb.w = fminf(fmaxf(cy + h * 0.5f, 0.f), 1.f) * 448.f;
        *reinterpret_cast<float4*>(&bxs[n * 4]) = bb;
    }
    __syncthreads();

    // ---- adjacency rows, only for union-candidate boxes ----
    if (tid < 4 * kN) {
        const int i = tid % kN;       // consecutive lanes -> consecutive i
        const int w = tid / kN;       // word index 0..3
        const int cell = i >> 1, k = i & 1;
        const float conf = xs[cell * kFeat + 28 + k];
        const float mp = maxp[cell];
        if (conf * mp >= kScoreT) {   // box can be a candidate in some class
            const float ax1 = bxs[i * 4 + 0], ay1 = bxs[i * 4 + 1];
            const float ax2 = bxs[i * 4 + 2], ay2 = bxs[i * 4 + 3];
            unsigned m = 0;
            const int j0 = 32 * w;
            const int j1 = (j0 + 32 < kN) ? (j0 + 32) : kN;
            for (int j = j0; j < j1; ++j) {
                float v = iou_f(ax1, ay1, ax2, ay2,
                                bxs[j * 4 + 0], bxs[j * 4 + 1],
                                bxs[j * 4 + 2], bxs[j * 4 + 3]);
                if (v > kIouT) m |= (1u << (j - j0));
            }
            if (w < 2) reinterpret_cast<unsigned*>(adjLo)[2 * i + w] = m;
            else       reinterpret_cast<unsigned*>(adjHi)[2 * i + (w - 2)] = m;
        }
    }
    __syncthreads();

    // ---- per-class NMS: wave wv handles class wv, then wv+16 (waves 0-3) ----
    const int wv = tid >> 6;
    const int lane = tid & 63;
    for (int pass = 0; pass < 2; ++pass) {
        const int c = wv + 16 * pass;
        if (c >= kC) break;
        // candidacy over both halves (boxes lane and lane+64)
        float s0 = scT[c * kN + lane];
        bool c0 = (s0 >= kScoreT);
        float s1 = 0.f;
        bool c1 = false;
        if (lane < kN - 64) {
            s1 = scT[c * kN + 64 + lane];
            c1 = (s1 >= kScoreT);
        }
        const unsigned long long m0 = __ballot(c0);
        const unsigned long long m1 = __ballot(c1);
        const int K0 = __popcll(m0);
        const int K  = K0 + __popcll(m1);
        const unsigned long long lt = (1ull << lane) - 1ull;
        int p0 = 0, p1 = 0;
        if (c0) {
            p0 = __popcll(m0 & lt);
            cscore[wv][p0] = s0;
            cidx[wv][p0] = (unsigned short)lane;
        }
        if (c1) {
            p1 = K0 + __popcll(m1 & lt);
            cscore[wv][p1] = s1;
            cidx[wv][p1] = (unsigned short)(lane + 64);
        }
        __builtin_amdgcn_wave_barrier();

        unsigned long long kb0 = 0, kb1 = 0;   // keep ballots (box space)
        if (K <= 64) {
            // rank = # candidates strictly ahead in (score desc, box-idx asc)
            const bool act = (lane < K);
            const float sp = act ? cscore[wv][lane] : 0.f;
            int rp = 0;
            for (int q = 0; q < K; ++q) {
                float sq = cscore[wv][q];                 // broadcast read
                rp += ((sq > sp) || ((sq == sp) && (q < lane))) ? 1 : 0;
            }
            if (act) {
                rnk[wv][lane] = (unsigned short)rp;
                rid[wv][rp] = cidx[wv][lane];
            }
            __builtin_amdgcn_wave_barrier();
            // lane r holds rank-r box id and its adjacency row (registers)
            const int myb = act ? (int)rid[wv][lane] : 0;
            const unsigned long long rLo = adjLo[myb];    // 8B stride: free
            const unsigned long long rHi = adjHi[myb];
            unsigned long long supLo = 0, supHi = 0, keepM = 0;
            for (int r = 0; r < K; ++r) {
                const int bi = __shfl(myb, r);            // indep of sup chain
                const unsigned long long qLo = shfl64(rLo, r);
                const unsigned long long qHi = shfl64(rHi, r);
                const unsigned long long word = (bi & 64) ? supHi : supLo;
                const unsigned long long bit = (word >> (bi & 63)) & 1ull;
                const unsigned long long take = bit - 1ull; // ~0 if still alive
                keepM |= (1ull << r) & take;
                supLo |= qLo & take;
                supHi |= qHi & take;
            }
            const bool k0 = c0 && ((keepM >> rnk[wv][p0]) & 1ull);
            const bool k1 = c1 && ((keepM >> rnk[wv][p1]) & 1ull);
            kb0 = __ballot(k0);
            kb1 = __ballot(k1);
        } else {
            // fallback (K>64, probability ~0): ballot-greedy over candidates
            bool al0 = c0, al1 = c1;
            bool k0 = false, k1 = false;
            const float n0x1 = bxs[lane * 4 + 0], n0y1 = bxs[lane * 4 + 1];
            const float n0x2 = bxs[lane * 4 + 2], n0y2 = bxs[lane * 4 + 3];
            float n1x1 = 0.f, n1y1 = 0.f, n1x2 = 0.f, n1y2 = 0.f;
            if (lane < kN - 64) {
                n1x1 = bxs[(lane + 64) * 4 + 0]; n1y1 = bxs[(lane + 64) * 4 + 1];
                n1x2 = bxs[(lane + 64) * 4 + 2]; n1y2 = bxs[(lane + 64) * 4 + 3];
            }
            for (;;) {
                float bs; int bp;
                if (al0 && (!al1 || s0 >= s1)) { bs = s0; bp = p0; }
                else if (al1)                  { bs = s1; bp = p1; }
                else                           { bs = -1e30f; bp = 1 << 20; }
                for (int off = 32; off; off >>= 1) {
                    float os = __shfl_xor(bs, off);
                    int   op = __shfl_xor(bp, off);
                    if (os > bs || (os == bs && op < bp)) { bs = os; bp = op; }
                }
                if (bp >= (1 << 20)) break;
                const int bi = cidx[wv][bp];              // wave-uniform
                const float4 kbx = *reinterpret_cast<const float4*>(&bxs[bi * 4]);
                if (bp == p0 && al0) { k0 = true; al0 = false; }
                if (bp == p1 && al1) { k1 = true; al1 = false; }
                if (al0 && iou_f(kbx.x, kbx.y, kbx.z, kbx.w,
                                 n0x1, n0y1, n0x2, n0y2) > kIouT) al0 = false;
                if (al1 && iou_f(kbx.x, kbx.y, kbx.z, kbx.w,
                                 n1x1, n1y1, n1x2, n1y2) > kIouT) al1 = false;
            }
            kb0 = __ballot(k0);
            kb1 = __ballot(k1);
        }
        if (lane == 0) {
            km[c][0] = (unsigned)kb0;
            km[c][1] = (unsigned)(kb0 >> 32);
            km[c][2] = (unsigned)kb1;
            km[c][3] = (unsigned)(kb1 >> 32);
        }
    }
    __syncthreads();

    // ---- writer: thread j emits rows 2j,2j+1 (same n) as 3 float4 ----
    if (tid < kRows / 2) {
        const int j = tid;
        const int r0 = 2 * j;
        const int n = r0 / kC;                // = j/10; rows 2j,2j+1 share n
        const int c0i = r0 - kC * n;          // even
        const int c1i = c0i + 1;
        const float4 bb = *reinterpret_cast<const float4*>(&bxs[n * 4]);
        const float sA = scT[c0i * kN + n];
        const float sB = scT[c1i * kN + n];
        const unsigned w = km[c0i][n >> 5];   // same word for both classes? no:
        const unsigned kA = (km[c0i][n >> 5] >> (n & 31)) & 1u;
        const unsigned kB = (km[c1i][n >> 5] >> (n & 31)) & 1u;
        (void)w;
        const float mA = kA ? 1.f : 0.f;
        const float mB = kB ? 1.f : 0.f;
        float* ob = out + (size_t)b * kOutF + (size_t)12 * j;
        float4 q0, q1, q2;
        q0.x = mA * (float)c0i; q0.y = mA * bb.x; q0.z = mA * bb.y; q0.w = mA * bb.z;
        q1.x = mA * bb.w;       q1.y = mA * sA;   q1.z = mB * (float)c1i; q1.w = mB * bb.x;
        q2.x = mB * bb.y;       q2.y = mB * bb.z; q2.z = mB * bb.w;       q2.w = mB * sB;
        reinterpret_cast<float4*>(ob)[0] = q0;
        reinterpret_cast<float4*>(ob)[1] = q1;
        reinterpret_cast<float4*>(ob)[2] = q2;
    }
}

extern "C" void kernel_launch(void* const* d_in, const int* in_sizes, int n_in,
                              void* d_out, int out_size, void* d_ws, size_t ws_size,
                              hipStream_t stream) {
    const float* x = (const float*)d_in[0];
    float* out = (float*)d_out;
    const int B = in_sizes[0] / (kS * kS * kFeat);   // 1024
    hipLaunchKernelGGL(yolo_head_kernel, dim3(B), dim3(kT), 0, stream, x, out);
}